// Round 16
// baseline (118.362 us; speedup 1.0000x reference)
//
#include <hip/hip_runtime.h>

// Shapes (fixed by the reference):
//   style_encoding (16,512,4,4)  content (16,512,64,64)
//   dw_w (4096,64,2,2)  dw_b (4096)  pw_kn_w (4096,64,1,1) pw_kn_b (4096)
//   pw_bias_w (512,512,1,1) pw_bias_b (512)
//   out (16,512,64,64) f32
//
// ANCHOR (R14/R15, passes at ~109.5 µs). SINGLE delta this round: k_main
// drops its first barrier — pack reads mean/rstd directly from ws (global,
// L2-broadcast) instead of LDS s_ms, so pack needs no cross-thread sync.
// Banned (deterministic fails): multi-tile-per-block k_main (R5-R8),
// k_stats+k_pred merged into one grid (R9).

#define N_B 16
#define CH  512
#define SP  4096   // 64*64

// workspace layout (floats)
#define WS_MEAN 0
#define WS_RSTD 8192
#define WS_SD   16384
#define WS_PWB  24576                 // [16][512]
#define WS_W    32768                 // [16][64][512 dwords] fused f16-packed weights

typedef float f32x4 __attribute__((ext_vector_type(4)));

__device__ __forceinline__ unsigned pk16(float x, float y) {
    auto h = __builtin_amdgcn_cvt_pkrtz(x, y);
    unsigned u; __builtin_memcpy(&u, &h, 4); return u;
}
__device__ __forceinline__ float f16lo(unsigned u) {
    unsigned short s = (unsigned short)u; _Float16 h;
    __builtin_memcpy(&h, &s, 2); return (float)h;
}
__device__ __forceinline__ float f16hi(unsigned u) {
    unsigned short s = (unsigned short)(u >> 16); _Float16 h;
    __builtin_memcpy(&h, &s, 2); return (float)h;
}
// acc += a(f16x2) . b(f16x2), f32 accumulate
__device__ __forceinline__ float dot2(unsigned a, unsigned b, float c) {
    asm("v_dot2_f32_f16 %0, %1, %2, %0" : "+v"(c) : "v"(a), "v"(b));
    return c;
}

// ---------------------------------------------------------------- stats ----
__global__ __launch_bounds__(256) void k_stats(const float* __restrict__ content,
                                               const float* __restrict__ style,
                                               float* __restrict__ ws) {
    int bid = blockIdx.x;
    int t = threadIdx.x;
    if (bid < N_B * CH) {
        const float4* row = (const float4*)(content + (size_t)bid * SP);
        float s = 0.f, ss = 0.f;
        for (int k = t; k < SP / 4; k += 256) {
            float4 v = row[k];
            s  += v.x + v.y + v.z + v.w;
            ss += v.x * v.x + v.y * v.y + v.z * v.z + v.w * v.w;
        }
        #pragma unroll
        for (int o = 32; o > 0; o >>= 1) {
            s  += __shfl_down(s, o);
            ss += __shfl_down(ss, o);
        }
        __shared__ float red[8];
        int w = t >> 6;
        if ((t & 63) == 0) { red[w] = s; red[4 + w] = ss; }
        __syncthreads();
        if (t == 0) {
            s  = red[0] + red[1] + red[2] + red[3];
            ss = red[4] + red[5] + red[6] + red[7];
            float mean = s * (1.0f / SP);
            float var  = (ss - s * mean) * (1.0f / (SP - 1));
            ws[WS_MEAN + bid] = mean;
            ws[WS_RSTD + bid] = rsqrtf(var + 1e-5f);
        }
    } else {
        int idx = (bid - N_B * CH) * 256 + t;        // 0..8191
        const float* p = style + (size_t)idx * 16;
        float s = 0.f;
        #pragma unroll
        for (int k = 0; k < 16; ++k) s += p[k];
        ws[WS_SD + idx] = s * (1.0f / 16.0f);
    }
}

// --------------------------- fused predictor: dw + pw_kn + pw_bias + fold ----
// block = (n, g). Produces per-(n,g): pwb[8] and packed fused weights
// W[j2][i]: d0=(k00,k01) d1=(k10,k11) d2=(k20,k21) d3=(k02,k12) d4=k22(f32), 8 dwords.
__global__ __launch_bounds__(256) void k_pred(const float* __restrict__ style,
                                              const float* __restrict__ dw_w,
                                              const float* __restrict__ dw_b,
                                              const float* __restrict__ pw_kn_w,
                                              const float* __restrict__ pw_kn_b,
                                              const float* __restrict__ pw_bias_w,
                                              const float* __restrict__ pw_bias_b,
                                              float* __restrict__ ws) {
    int n = blockIdx.x >> 6, g = blockIdx.x & 63, sg = g >> 3;
    __shared__ float s_st[64 * 16];
    __shared__ float s_sd[512];
    __shared__ float s_dwk[64 * 9];
    __shared__ float s_pwk[64];
    __shared__ float s_W[64 * 9];
    int t = threadIdx.x;

    for (int idx = t; idx < 1024; idx += 256)
        s_st[idx] = style[((size_t)n * CH + sg * 64) * 16 + idx];
    for (int idx = t; idx < 512; idx += 256)
        s_sd[idx] = ws[WS_SD + n * 512 + idx];
    __syncthreads();

    if (t < 192) {
        // depthwise predictor: oc_l = t&63, row ky = t>>6, 3 taps each
        int oc_l = t & 63, ky = t >> 6;
        int oc = g * 64 + oc_l;
        const float4* wp = (const float4*)(dw_w + (size_t)oc * 256);
        float a0 = 0.f, a1 = 0.f, a2 = 0.f;
        for (int ic = 0; ic < 64; ++ic) {
            float4 w = wp[ic];
            const float* sp = s_st + ic * 16 + ky * 4;
            a0 += w.x * sp[0] + w.y * sp[1] + w.z * sp[4] + w.w * sp[5];
            a1 += w.x * sp[1] + w.y * sp[2] + w.z * sp[5] + w.w * sp[6];
            a2 += w.x * sp[2] + w.y * sp[3] + w.z * sp[6] + w.w * sp[7];
        }
        float b = dw_b[oc];
        s_dwk[oc_l * 9 + ky * 3 + 0] = fmaxf(a0 + b, 0.f);
        s_dwk[oc_l * 9 + ky * 3 + 1] = fmaxf(a1 + b, 0.f);
        s_dwk[oc_l * 9 + ky * 3 + 2] = fmaxf(a2 + b, 0.f);
    } else {
        int L = t - 192;                       // lane 0..63 of wave 3
        // pointwise-kernel predictor (one 64-dot per L)
        {
            const float4* wp = (const float4*)(pw_kn_w + (size_t)(g * 64 + L) * 64);
            const float* sp = s_sd + sg * 64;
            float a = 0.f;
            #pragma unroll
            for (int k = 0; k < 16; ++k) {
                float4 w = wp[k];
                a += w.x * sp[k * 4] + w.y * sp[k * 4 + 1] + w.z * sp[k * 4 + 2] + w.w * sp[k * 4 + 3];
            }
            s_pwk[L] = fmaxf(a + pw_kn_b[g * 64 + L], 0.f);
        }
        // pointwise-bias predictor: 8 outputs x 8 lanes (64-chunk each)
        {
            int j2 = L >> 3, ch = L & 7;
            int c2 = g * 8 + j2;
            const float4* bp = (const float4*)(pw_bias_w + (size_t)c2 * 512 + ch * 64);
            const float* sq = s_sd + ch * 64;
            float s = 0.f;
            #pragma unroll
            for (int k = 0; k < 16; ++k) {
                float4 w = bp[k];
                s += w.x * sq[k * 4] + w.y * sq[k * 4 + 1] + w.z * sq[k * 4 + 2] + w.w * sq[k * 4 + 3];
            }
            s += __shfl_down(s, 4);
            s += __shfl_down(s, 2);
            s += __shfl_down(s, 1);
            if (ch == 0) ws[WS_PWB + n * 512 + c2] = fmaxf(s + pw_bias_b[c2], 0.f);
        }
    }
    __syncthreads();

    // fold pointwise into depthwise: W[j2][i][tap] = sum_j pwk[j2*8+j]*dwk[(j*8+i)][tap]
    for (int job = t; job < 576; job += 256) {
        int tap = job % 9, ji = job / 9;
        int j2 = ji >> 3, i = ji & 7;
        float a = 0.f;
        #pragma unroll
        for (int j = 0; j < 8; ++j)
            a += s_pwk[j2 * 8 + j] * s_dwk[(j * 8 + i) * 9 + tap];
        s_W[ji * 9 + tap] = a;
    }
    __syncthreads();

    // pack to f16 pairs
    unsigned* wout = (unsigned*)(ws + WS_W) + (size_t)(n * 64 + g) * 512;
    for (int job = t; job < 512; job += 256) {
        int ji = job >> 3, d2 = job & 7;
        const float* Wp = s_W + ji * 9;
        unsigned v = 0;
        if      (d2 == 0) v = pk16(Wp[0], Wp[1]);
        else if (d2 == 1) v = pk16(Wp[3], Wp[4]);
        else if (d2 == 2) v = pk16(Wp[6], Wp[7]);
        else if (d2 == 3) v = pk16(Wp[2], Wp[5]);
        else if (d2 == 4) { float f = Wp[8]; __builtin_memcpy(&v, &f, 4); }
        wout[job] = v;
    }
}

// ------------------------------------------------------- fused main op ----
// block = (n, group g, 16-row tile ty). LDS tile f16: position p = col p-1,
// row stride 72 (p=0..65 used). Reflect: pos0=col1, pos65=col62.
// SINGLE DELTA vs R15: first barrier removed — pack reads mean/rstd straight
// from ws (global); s_ms deleted; s_w/s_wb protected by the post-pack barrier.
#define TST 72
__global__ __launch_bounds__(256, 6) void k_main(const float* __restrict__ content,
                                                 const float* __restrict__ ws,
                                                 float* __restrict__ out) {
    int bid = blockIdx.x;
    int ty = bid & 3, g = (bid >> 2) & 63, n = bid >> 8;
    __shared__ __align__(16) unsigned short cn[8][18][TST];
    __shared__ __align__(16) unsigned s_w[512];
    __shared__ float s_wb[8];

    int t = threadIdx.x;

    // ---- issue the 9 stage loads FIRST (independent of LDS staging) ----
    int y0 = ty * 16;
    int q = t & 15, grp = t >> 4;
    const float* cbase = content + ((size_t)(n * CH + g * 8)) * SP;
    float4 ld[9];
    #pragma unroll
    for (int cc = 0; cc < 9; ++cc) {
        int rowid = cc * 16 + grp;            // 0..143
        int i = rowid / 18, r = rowid - i * 18;
        int gy = y0 + r - 1;
        gy = gy < 0 ? 1 : (gy > 63 ? 62 : gy);
        ld[cc] = *(const float4*)(cbase + (size_t)i * SP + gy * 64 + 4 * q);
    }

    // ---- stage weights while the loads are in flight (no barrier yet) ----
    {
        const float4* wsrc = (const float4*)(ws + WS_W) + (size_t)(n * 64 + g) * 128;
        if (t < 128) ((float4*)s_w)[t] = wsrc[t];
        if (t < 8) s_wb[t] = ws[WS_PWB + n * 512 + g * 8 + t];
    }

    // ---- pack + LDS write (mean/rstd read directly from ws, L2-broadcast) ----
    const float* msM = ws + WS_MEAN + n * 512 + g * 8;
    const float* msR = ws + WS_RSTD + n * 512 + g * 8;
    #pragma unroll
    for (int cc = 0; cc < 9; ++cc) {
        int rowid = cc * 16 + grp;
        int i = rowid / 18, r = rowid - i * 18;
        float sA = msR[i];                    // rstd
        float sB = -msM[i] * sA;              // -mean*rstd
        float4 v = ld[cc];
        unsigned u0 = pk16(fmaf(v.x, sA, sB), fmaf(v.y, sA, sB));
        unsigned u1 = pk16(fmaf(v.z, sA, sB), fmaf(v.w, sA, sB));
        unsigned pu1 = __shfl_up(u1, 1);
        if (q == 0) pu1 = u0;                  // pos0 = reflect(col1)
        uint2 o;
        o.x = (pu1 >> 16) | (u0 << 16);        // positions 4q,4q+1
        o.y = (u0 >> 16) | (u1 << 16);         // positions 4q+2,4q+3
        *(uint2*)&cn[i][r][4 * q] = o;
        if (q == 15)                           // positions 64,65 = cols 63,62
            *(unsigned*)&cn[i][r][64] = (u1 >> 16) | (u1 << 16);
    }
    __syncthreads();   // protects cn AND s_w/s_wb

    // ---- compute: thread owns 4 px (row r_o, cols x0..x0+3) ----
    int r_o = t >> 4, k16 = t & 15, x0 = k16 << 2;
    float acc[8][4];
    #pragma unroll
    for (int j = 0; j < 8; ++j)
        #pragma unroll
        for (int p = 0; p < 4; ++p) acc[j][p] = 0.f;

    for (int i = 0; i < 8; ++i) {
        unsigned R0[3], R1[3], R2[3];
        #pragma unroll
        for (int ky = 0; ky < 3; ++ky) {
            const unsigned short* rp = &cn[i][r_o + ky][4 * k16];
            uint2 a = *(const uint2*)rp;               // positions x0..x0+3
            unsigned b = *(const unsigned*)(rp + 4);   // positions x0+4,x0+5
            R0[ky] = a.x; R1[ky] = a.y; R2[ky] = b;
        }
        unsigned pr[3][4];
        #pragma unroll
        for (int ky = 0; ky < 3; ++ky) {
            pr[ky][0] = R0[ky];
            pr[ky][1] = __builtin_amdgcn_alignbit(R1[ky], R0[ky], 16);
            pr[ky][2] = R1[ky];
            pr[ky][3] = __builtin_amdgcn_alignbit(R2[ky], R1[ky], 16);
        }
        unsigned cp[4];
        cp[0] = __builtin_amdgcn_perm(R1[1], R1[0], 0x05040100u);  // (lo,lo)
        cp[1] = __builtin_amdgcn_perm(R1[1], R1[0], 0x07060302u);  // (hi,hi)
        cp[2] = __builtin_amdgcn_perm(R2[1], R2[0], 0x05040100u);
        cp[3] = __builtin_amdgcn_perm(R2[1], R2[0], 0x07060302u);
        float sf[4] = { f16lo(R1[2]), f16hi(R1[2]), f16lo(R2[2]), f16hi(R2[2]) };
        #pragma unroll
        for (int j2 = 0; j2 < 8; ++j2) {
            const unsigned* wb = &s_w[(j2 * 8 + i) * 8];
            uint4 d = *(const uint4*)wb;
            float k22 = ((const float*)wb)[4];
            #pragma unroll
            for (int p = 0; p < 4; ++p) {
                float a = acc[j2][p];
                a = dot2(d.x, pr[0][p], a);
                a = dot2(d.y, pr[1][p], a);
                a = dot2(d.z, pr[2][p], a);
                a = dot2(d.w, cp[p], a);
                acc[j2][p] = fmaf(k22, sf[p], a);
            }
        }
    }

    // ---- bias + leaky(0.01) + cn add + NT store ----
    size_t obase = ((size_t)(n * CH + g * 8) * 64 + (y0 + r_o)) * 64 + x0;
    #pragma unroll
    for (int j2 = 0; j2 < 8; ++j2) {
        const unsigned short* rp = &cn[j2][r_o + 1][4 * k16];
        uint2 a = *(const uint2*)rp;
        unsigned b = *(const unsigned*)(rp + 4);
        float cv[4] = { f16hi(a.x), f16lo(a.y), f16hi(a.y), f16lo(b) };
        float bias = s_wb[j2];
        f32x4 o;
        #pragma unroll
        for (int p = 0; p < 4; ++p) {
            float v = acc[j2][p] + bias;
            v = v > 0.f ? v : 0.01f * v;
            o[p] = v + cv[p];
        }
        __builtin_nontemporal_store(o, (f32x4*)(out + obase + (size_t)j2 * SP));
    }
}

extern "C" void kernel_launch(void* const* d_in, const int* in_sizes, int n_in,
                              void* d_out, int out_size, void* d_ws, size_t ws_size,
                              hipStream_t stream) {
    const float* style     = (const float*)d_in[0];
    const float* content   = (const float*)d_in[1];
    const float* dw_w      = (const float*)d_in[2];
    const float* dw_b      = (const float*)d_in[3];
    const float* pw_kn_w   = (const float*)d_in[4];
    const float* pw_kn_b   = (const float*)d_in[5];
    const float* pw_bias_w = (const float*)d_in[6];
    const float* pw_bias_b = (const float*)d_in[7];
    float* out = (float*)d_out;
    float* ws  = (float*)d_ws;

    k_stats<<<dim3(N_B * CH + 32), dim3(256), 0, stream>>>(content, style, ws);
    k_pred <<<dim3(1024),          dim3(256), 0, stream>>>(style, dw_w, dw_b, pw_kn_w,
                                                           pw_kn_b, pw_bias_w, pw_bias_b, ws);
    k_main <<<dim3(4096),          dim3(256), 0, stream>>>(content, ws, out);
}

// Round 17
// 108.534 us; speedup vs baseline: 1.0905x; 1.0905x over previous
//
#include <hip/hip_runtime.h>

// Shapes (fixed by the reference):
//   style_encoding (16,512,4,4)  content (16,512,64,64)
//   dw_w (4096,64,2,2)  dw_b (4096)  pw_kn_w (4096,64,1,1) pw_kn_b (4096)
//   pw_bias_w (512,512,1,1) pw_bias_b (512)
//   out (16,512,64,64) f32
//
// FINAL (R14 configuration, best measured: 109.2 µs).
// k_main: 4096 blocks, ONE 16-row tile per block; ld[9] hoisted batch load
// AFTER the weights barrier (the barrier pins the load cluster — removing it
// lets the compiler sink loads and costs 9 µs, R16).
// Banned (deterministic fails): multi-tile-per-block k_main (R5-R8),
// k_stats+k_pred merged into one grid (R9).

#define N_B 16
#define CH  512
#define SP  4096   // 64*64

// workspace layout (floats)
#define WS_MEAN 0
#define WS_RSTD 8192
#define WS_SD   16384
#define WS_PWB  24576                 // [16][512]
#define WS_W    32768                 // [16][64][512 dwords] fused f16-packed weights

typedef float f32x4 __attribute__((ext_vector_type(4)));

__device__ __forceinline__ unsigned pk16(float x, float y) {
    auto h = __builtin_amdgcn_cvt_pkrtz(x, y);
    unsigned u; __builtin_memcpy(&u, &h, 4); return u;
}
__device__ __forceinline__ float f16lo(unsigned u) {
    unsigned short s = (unsigned short)u; _Float16 h;
    __builtin_memcpy(&h, &s, 2); return (float)h;
}
__device__ __forceinline__ float f16hi(unsigned u) {
    unsigned short s = (unsigned short)(u >> 16); _Float16 h;
    __builtin_memcpy(&h, &s, 2); return (float)h;
}
// acc += a(f16x2) . b(f16x2), f32 accumulate
__device__ __forceinline__ float dot2(unsigned a, unsigned b, float c) {
    asm("v_dot2_f32_f16 %0, %1, %2, %0" : "+v"(c) : "v"(a), "v"(b));
    return c;
}

// ---------------------------------------------------------------- stats ----
__global__ __launch_bounds__(256) void k_stats(const float* __restrict__ content,
                                               const float* __restrict__ style,
                                               float* __restrict__ ws) {
    int bid = blockIdx.x;
    int t = threadIdx.x;
    if (bid < N_B * CH) {
        const float4* row = (const float4*)(content + (size_t)bid * SP);
        float s = 0.f, ss = 0.f;
        for (int k = t; k < SP / 4; k += 256) {
            float4 v = row[k];
            s  += v.x + v.y + v.z + v.w;
            ss += v.x * v.x + v.y * v.y + v.z * v.z + v.w * v.w;
        }
        #pragma unroll
        for (int o = 32; o > 0; o >>= 1) {
            s  += __shfl_down(s, o);
            ss += __shfl_down(ss, o);
        }
        __shared__ float red[8];
        int w = t >> 6;
        if ((t & 63) == 0) { red[w] = s; red[4 + w] = ss; }
        __syncthreads();
        if (t == 0) {
            s  = red[0] + red[1] + red[2] + red[3];
            ss = red[4] + red[5] + red[6] + red[7];
            float mean = s * (1.0f / SP);
            float var  = (ss - s * mean) * (1.0f / (SP - 1));
            ws[WS_MEAN + bid] = mean;
            ws[WS_RSTD + bid] = rsqrtf(var + 1e-5f);
        }
    } else {
        int idx = (bid - N_B * CH) * 256 + t;        // 0..8191
        const float* p = style + (size_t)idx * 16;
        float s = 0.f;
        #pragma unroll
        for (int k = 0; k < 16; ++k) s += p[k];
        ws[WS_SD + idx] = s * (1.0f / 16.0f);
    }
}

// --------------------------- fused predictor: dw + pw_kn + pw_bias + fold ----
// block = (n, g). Produces per-(n,g): pwb[8] and packed fused weights
// W[j2][i]: d0=(k00,k01) d1=(k10,k11) d2=(k20,k21) d3=(k02,k12) d4=k22(f32), 8 dwords.
__global__ __launch_bounds__(256) void k_pred(const float* __restrict__ style,
                                              const float* __restrict__ dw_w,
                                              const float* __restrict__ dw_b,
                                              const float* __restrict__ pw_kn_w,
                                              const float* __restrict__ pw_kn_b,
                                              const float* __restrict__ pw_bias_w,
                                              const float* __restrict__ pw_bias_b,
                                              float* __restrict__ ws) {
    int n = blockIdx.x >> 6, g = blockIdx.x & 63, sg = g >> 3;
    __shared__ float s_st[64 * 16];
    __shared__ float s_sd[512];
    __shared__ float s_dwk[64 * 9];
    __shared__ float s_pwk[64];
    __shared__ float s_W[64 * 9];
    int t = threadIdx.x;

    for (int idx = t; idx < 1024; idx += 256)
        s_st[idx] = style[((size_t)n * CH + sg * 64) * 16 + idx];
    for (int idx = t; idx < 512; idx += 256)
        s_sd[idx] = ws[WS_SD + n * 512 + idx];
    __syncthreads();

    if (t < 192) {
        // depthwise predictor: oc_l = t&63, row ky = t>>6, 3 taps each
        int oc_l = t & 63, ky = t >> 6;
        int oc = g * 64 + oc_l;
        const float4* wp = (const float4*)(dw_w + (size_t)oc * 256);
        float a0 = 0.f, a1 = 0.f, a2 = 0.f;
        for (int ic = 0; ic < 64; ++ic) {
            float4 w = wp[ic];
            const float* sp = s_st + ic * 16 + ky * 4;
            a0 += w.x * sp[0] + w.y * sp[1] + w.z * sp[4] + w.w * sp[5];
            a1 += w.x * sp[1] + w.y * sp[2] + w.z * sp[5] + w.w * sp[6];
            a2 += w.x * sp[2] + w.y * sp[3] + w.z * sp[6] + w.w * sp[7];
        }
        float b = dw_b[oc];
        s_dwk[oc_l * 9 + ky * 3 + 0] = fmaxf(a0 + b, 0.f);
        s_dwk[oc_l * 9 + ky * 3 + 1] = fmaxf(a1 + b, 0.f);
        s_dwk[oc_l * 9 + ky * 3 + 2] = fmaxf(a2 + b, 0.f);
    } else {
        int L = t - 192;                       // lane 0..63 of wave 3
        // pointwise-kernel predictor (one 64-dot per L)
        {
            const float4* wp = (const float4*)(pw_kn_w + (size_t)(g * 64 + L) * 64);
            const float* sp = s_sd + sg * 64;
            float a = 0.f;
            #pragma unroll
            for (int k = 0; k < 16; ++k) {
                float4 w = wp[k];
                a += w.x * sp[k * 4] + w.y * sp[k * 4 + 1] + w.z * sp[k * 4 + 2] + w.w * sp[k * 4 + 3];
            }
            s_pwk[L] = fmaxf(a + pw_kn_b[g * 64 + L], 0.f);
        }
        // pointwise-bias predictor: 8 outputs x 8 lanes (64-chunk each)
        {
            int j2 = L >> 3, ch = L & 7;
            int c2 = g * 8 + j2;
            const float4* bp = (const float4*)(pw_bias_w + (size_t)c2 * 512 + ch * 64);
            const float* sq = s_sd + ch * 64;
            float s = 0.f;
            #pragma unroll
            for (int k = 0; k < 16; ++k) {
                float4 w = bp[k];
                s += w.x * sq[k * 4] + w.y * sq[k * 4 + 1] + w.z * sq[k * 4 + 2] + w.w * sq[k * 4 + 3];
            }
            s += __shfl_down(s, 4);
            s += __shfl_down(s, 2);
            s += __shfl_down(s, 1);
            if (ch == 0) ws[WS_PWB + n * 512 + c2] = fmaxf(s + pw_bias_b[c2], 0.f);
        }
    }
    __syncthreads();

    // fold pointwise into depthwise: W[j2][i][tap] = sum_j pwk[j2*8+j]*dwk[(j*8+i)][tap]
    for (int job = t; job < 576; job += 256) {
        int tap = job % 9, ji = job / 9;
        int j2 = ji >> 3, i = ji & 7;
        float a = 0.f;
        #pragma unroll
        for (int j = 0; j < 8; ++j)
            a += s_pwk[j2 * 8 + j] * s_dwk[(j * 8 + i) * 9 + tap];
        s_W[ji * 9 + tap] = a;
    }
    __syncthreads();

    // pack to f16 pairs
    unsigned* wout = (unsigned*)(ws + WS_W) + (size_t)(n * 64 + g) * 512;
    for (int job = t; job < 512; job += 256) {
        int ji = job >> 3, d2 = job & 7;
        const float* Wp = s_W + ji * 9;
        unsigned v = 0;
        if      (d2 == 0) v = pk16(Wp[0], Wp[1]);
        else if (d2 == 1) v = pk16(Wp[3], Wp[4]);
        else if (d2 == 2) v = pk16(Wp[6], Wp[7]);
        else if (d2 == 3) v = pk16(Wp[2], Wp[5]);
        else if (d2 == 4) { float f = Wp[8]; __builtin_memcpy(&v, &f, 4); }
        wout[job] = v;
    }
}

// ------------------------------------------------------- fused main op ----
// block = (n, group g, 16-row tile ty). LDS tile f16: position p = col p-1,
// row stride 72 (p=0..65 used). Reflect: pos0=col1, pos65=col62.
// Stage: ld[9] batch load after the weights barrier (barrier pins the batch).
#define TST 72
__global__ __launch_bounds__(256, 6) void k_main(const float* __restrict__ content,
                                                 const float* __restrict__ ws,
                                                 float* __restrict__ out) {
    int bid = blockIdx.x;
    int ty = bid & 3, g = (bid >> 2) & 63, n = bid >> 8;
    __shared__ __align__(16) unsigned short cn[8][18][TST];
    __shared__ __align__(16) unsigned s_w[512];
    __shared__ float s_wb[8];
    __shared__ float s_ms[16];

    int t = threadIdx.x;
    {
        const float4* wsrc = (const float4*)(ws + WS_W) + (size_t)(n * 64 + g) * 128;
        if (t < 128) ((float4*)s_w)[t] = wsrc[t];
        if (t < 8) {
            s_wb[t]     = ws[WS_PWB + n * 512 + g * 8 + t];
            s_ms[t]     = ws[WS_MEAN + n * 512 + g * 8 + t];
            s_ms[8 + t] = ws[WS_RSTD + n * 512 + g * 8 + t];
        }
    }
    __syncthreads();

    // ---- stage: 144 (ch,row) segments, 16 lanes each ----
    // all 9 loads issued first (in flight together), then pack+write
    int y0 = ty * 16;
    int q = t & 15, grp = t >> 4;
    const float* cbase = content + ((size_t)(n * CH + g * 8)) * SP;
    float4 ld[9];
    #pragma unroll
    for (int cc = 0; cc < 9; ++cc) {
        int rowid = cc * 16 + grp;            // 0..143
        int i = rowid / 18, r = rowid - i * 18;
        int gy = y0 + r - 1;
        gy = gy < 0 ? 1 : (gy > 63 ? 62 : gy);
        ld[cc] = *(const float4*)(cbase + (size_t)i * SP + gy * 64 + 4 * q);
    }
    #pragma unroll
    for (int cc = 0; cc < 9; ++cc) {
        int rowid = cc * 16 + grp;
        int i = rowid / 18, r = rowid - i * 18;
        float sA = s_ms[8 + i];               // rstd
        float sB = -s_ms[i] * sA;             // -mean*rstd
        float4 v = ld[cc];
        unsigned u0 = pk16(fmaf(v.x, sA, sB), fmaf(v.y, sA, sB));
        unsigned u1 = pk16(fmaf(v.z, sA, sB), fmaf(v.w, sA, sB));
        unsigned pu1 = __shfl_up(u1, 1);
        if (q == 0) pu1 = u0;                  // pos0 = reflect(col1)
        uint2 o;
        o.x = (pu1 >> 16) | (u0 << 16);        // positions 4q,4q+1
        o.y = (u0 >> 16) | (u1 << 16);         // positions 4q+2,4q+3
        *(uint2*)&cn[i][r][4 * q] = o;
        if (q == 15)                           // positions 64,65 = cols 63,62
            *(unsigned*)&cn[i][r][64] = (u1 >> 16) | (u1 << 16);
    }
    __syncthreads();

    // ---- compute: thread owns 4 px (row r_o, cols x0..x0+3) ----
    int r_o = t >> 4, k16 = t & 15, x0 = k16 << 2;
    float acc[8][4];
    #pragma unroll
    for (int j = 0; j < 8; ++j)
        #pragma unroll
        for (int p = 0; p < 4; ++p) acc[j][p] = 0.f;

    for (int i = 0; i < 8; ++i) {
        unsigned R0[3], R1[3], R2[3];
        #pragma unroll
        for (int ky = 0; ky < 3; ++ky) {
            const unsigned short* rp = &cn[i][r_o + ky][4 * k16];
            uint2 a = *(const uint2*)rp;               // positions x0..x0+3
            unsigned b = *(const unsigned*)(rp + 4);   // positions x0+4,x0+5
            R0[ky] = a.x; R1[ky] = a.y; R2[ky] = b;
        }
        unsigned pr[3][4];
        #pragma unroll
        for (int ky = 0; ky < 3; ++ky) {
            pr[ky][0] = R0[ky];
            pr[ky][1] = __builtin_amdgcn_alignbit(R1[ky], R0[ky], 16);
            pr[ky][2] = R1[ky];
            pr[ky][3] = __builtin_amdgcn_alignbit(R2[ky], R1[ky], 16);
        }
        unsigned cp[4];
        cp[0] = __builtin_amdgcn_perm(R1[1], R1[0], 0x05040100u);  // (lo,lo)
        cp[1] = __builtin_amdgcn_perm(R1[1], R1[0], 0x07060302u);  // (hi,hi)
        cp[2] = __builtin_amdgcn_perm(R2[1], R2[0], 0x05040100u);
        cp[3] = __builtin_amdgcn_perm(R2[1], R2[0], 0x07060302u);
        float sf[4] = { f16lo(R1[2]), f16hi(R1[2]), f16lo(R2[2]), f16hi(R2[2]) };
        #pragma unroll
        for (int j2 = 0; j2 < 8; ++j2) {
            const unsigned* wb = &s_w[(j2 * 8 + i) * 8];
            uint4 d = *(const uint4*)wb;
            float k22 = ((const float*)wb)[4];
            #pragma unroll
            for (int p = 0; p < 4; ++p) {
                float a = acc[j2][p];
                a = dot2(d.x, pr[0][p], a);
                a = dot2(d.y, pr[1][p], a);
                a = dot2(d.z, pr[2][p], a);
                a = dot2(d.w, cp[p], a);
                acc[j2][p] = fmaf(k22, sf[p], a);
            }
        }
    }

    // ---- bias + leaky(0.01) + cn add + NT store ----
    size_t obase = ((size_t)(n * CH + g * 8) * 64 + (y0 + r_o)) * 64 + x0;
    #pragma unroll
    for (int j2 = 0; j2 < 8; ++j2) {
        const unsigned short* rp = &cn[j2][r_o + 1][4 * k16];
        uint2 a = *(const uint2*)rp;
        unsigned b = *(const unsigned*)(rp + 4);
        float cv[4] = { f16hi(a.x), f16lo(a.y), f16hi(a.y), f16lo(b) };
        float bias = s_wb[j2];
        f32x4 o;
        #pragma unroll
        for (int p = 0; p < 4; ++p) {
            float v = acc[j2][p] + bias;
            v = v > 0.f ? v : 0.01f * v;
            o[p] = v + cv[p];
        }
        __builtin_nontemporal_store(o, (f32x4*)(out + obase + (size_t)j2 * SP));
    }
}

extern "C" void kernel_launch(void* const* d_in, const int* in_sizes, int n_in,
                              void* d_out, int out_size, void* d_ws, size_t ws_size,
                              hipStream_t stream) {
    const float* style     = (const float*)d_in[0];
    const float* content   = (const float*)d_in[1];
    const float* dw_w      = (const float*)d_in[2];
    const float* dw_b      = (const float*)d_in[3];
    const float* pw_kn_w   = (const float*)d_in[4];
    const float* pw_kn_b   = (const float*)d_in[5];
    const float* pw_bias_w = (const float*)d_in[6];
    const float* pw_bias_b = (const float*)d_in[7];
    float* out = (float*)d_out;
    float* ws  = (float*)d_ws;

    k_stats<<<dim3(N_B * CH + 32), dim3(256), 0, stream>>>(content, style, ws);
    k_pred <<<dim3(1024),          dim3(256), 0, stream>>>(style, dw_w, dw_b, pw_kn_w,
                                                           pw_kn_b, pw_bias_w, pw_bias_b, ws);
    k_main <<<dim3(4096),          dim3(256), 0, stream>>>(content, ws, out);
}